// Round 2
// baseline (2192.502 us; speedup 1.0000x reference)
//
#include <hip/hip_runtime.h>
#include <hip/hip_bf16.h>

#define BQ   32
#define SEQ  1024
#define DM   768
#define NH   12
#define DH   64
#define CQKV 2304
#define MROWS (BQ * SEQ)   // 32768

typedef __attribute__((ext_vector_type(8))) short  short8;   // 8 bf16 = 4 VGPRs
typedef __attribute__((ext_vector_type(4))) float  floatx4;

using bf16 = __hip_bfloat16;

// ---------------------------------------------------------------------------
// Cast fp32 -> bf16, vectorized 4/thread. x is 25.17M elems (divisible by 4).
// ---------------------------------------------------------------------------
__global__ void cast_f32_bf16(const float* __restrict__ in, bf16* __restrict__ out,
                              int n4)
{
    int idx = blockIdx.x * blockDim.x + threadIdx.x;
    if (idx < n4) {
        float4 v = ((const float4*)in)[idx];
        bf16 o[4] = { __float2bfloat16(v.x), __float2bfloat16(v.y),
                      __float2bfloat16(v.z), __float2bfloat16(v.w) };
        ((ushort4*)out)[idx] = *(const ushort4*)o;
    }
}

// ---------------------------------------------------------------------------
// Transpose+cast: fp32 (R x C) -> bf16 (C x R).
// ---------------------------------------------------------------------------
__global__ void transpose_cast(const float* __restrict__ in, bf16* __restrict__ out,
                               int R, int C)
{
    int idx = blockIdx.x * blockDim.x + threadIdx.x;
    if (idx < R * C) {
        int r = idx / C, c = idx % C;
        out[(size_t)c * R + r] = __float2bfloat16(in[idx]);
    }
}

// ---------------------------------------------------------------------------
// QKV projection: Xb(32768x768 bf16) @ Wqkv + b -> Q[b,h,n,d], K[b,h,n,d],
// Vt[b,h,d,n].  WT is Wqkv^T (2304x768 bf16) so B-fragments are 16B row reads.
// Block: 256 thr = 4 waves; tile 64(M)x64(N); wave w does rows [m0+16w,+16).
// ---------------------------------------------------------------------------
__global__ __launch_bounds__(256) void gemm_qkv(
    const bf16* __restrict__ X, const bf16* __restrict__ WT,
    const float* __restrict__ bias,
    bf16* __restrict__ Qo, bf16* __restrict__ Ko, bf16* __restrict__ Vt)
{
    int w = threadIdx.x >> 6, lane = threadIdx.x & 63;
    int lr = lane & 15, lq = lane >> 4;       // A/B row = lane&15, quad = lane>>4
    int m0 = blockIdx.x * 64 + w * 16;
    int n0 = blockIdx.y * 64;

    const bf16* arow = X + (size_t)(m0 + lr) * DM;
    floatx4 acc[4] = {};
    for (int k0 = 0; k0 < DM; k0 += 32) {
        short8 a = *(const short8*)(arow + k0 + lq * 8);
        #pragma unroll
        for (int nt = 0; nt < 4; ++nt) {
            short8 b = *(const short8*)(WT + (size_t)(n0 + nt * 16 + lr) * DM + k0 + lq * 8);
            acc[nt] = __builtin_amdgcn_mfma_f32_16x16x32_bf16(a, b, acc[nt], 0, 0, 0);
        }
    }

    // Tile is 64-aligned in N, so `which` (q/k/v) and head h are block-uniform.
    int which = n0 / DM;
    int h     = (n0 % DM) / DH;
    #pragma unroll
    for (int nt = 0; nt < 4; ++nt) {
        int d = nt * 16 + lr;                             // C/D col = lane&15
        float bv = bias[n0 + nt * 16 + lr];
        #pragma unroll
        for (int r = 0; r < 4; ++r) {                     // C/D row = quad*4 + r
            int rg = m0 + lq * 4 + r;
            int bb = rg >> 10, n = rg & (SEQ - 1);
            bf16 o = __float2bfloat16(acc[nt][r] + bv);
            size_t head = (size_t)(bb * NH + h);
            if (which == 0)      Qo[(head * SEQ + n) * DH + d] = o;
            else if (which == 1) Ko[(head * SEQ + n) * DH + d] = o;
            else                 Vt[(head * DH + d) * SEQ + n] = o;
        }
    }
}

// ---------------------------------------------------------------------------
// Flash attention. Grid: (SEQ/64, NH, BQ). Block 256 = 4 waves; wave owns 16
// q-rows. KV tiles of 32. S = Q K^T via mfma (A=Q rows, B-frag = K rows since
// B^T = K). Online softmax with width-16 shuffles (C-layout row = quad*4+reg).
// P round-trips through LDS (C-layout -> A-layout). PV B-frags are contiguous
// 16B reads from Vt (= V^T). Output O is bf16 row-major (MROWS x DM).
// ---------------------------------------------------------------------------
__global__ __launch_bounds__(256) void flash_attn(
    const bf16* __restrict__ Q, const bf16* __restrict__ K,
    const bf16* __restrict__ Vt, bf16* __restrict__ O)
{
    __shared__ __align__(16) bf16 Plds[4][16][40];   // +8 pad, rows stay 16B aligned
    int w = threadIdx.x >> 6, lane = threadIdx.x & 63;
    int lr = lane & 15, lq = lane >> 4;
    int b = blockIdx.z, h = blockIdx.y;
    int m0 = blockIdx.x * 64 + w * 16;

    const bf16* Qh = Q  + (size_t)(b * NH + h) * SEQ * DH;
    const bf16* Kh = K  + (size_t)(b * NH + h) * SEQ * DH;
    const bf16* Vh = Vt + (size_t)(b * NH + h) * DH * SEQ;

    short8 aq0 = *(const short8*)(Qh + (m0 + lr) * DH + lq * 8);
    short8 aq1 = *(const short8*)(Qh + (m0 + lr) * DH + 32 + lq * 8);

    floatx4 acc[4] = {};
    float mi[4], li[4];
    #pragma unroll
    for (int r = 0; r < 4; ++r) { mi[r] = -1e30f; li[r] = 0.f; }

    for (int j0 = 0; j0 < SEQ; j0 += 32) {
        floatx4 s[2];
        #pragma unroll
        for (int jt = 0; jt < 2; ++jt) {
            short8 bk0 = *(const short8*)(Kh + (j0 + jt * 16 + lr) * DH + lq * 8);
            short8 bk1 = *(const short8*)(Kh + (j0 + jt * 16 + lr) * DH + 32 + lq * 8);
            floatx4 c = {};
            c = __builtin_amdgcn_mfma_f32_16x16x32_bf16(aq0, bk0, c, 0, 0, 0);
            c = __builtin_amdgcn_mfma_f32_16x16x32_bf16(aq1, bk1, c, 0, 0, 0);
            s[jt] = c;
        }
        float mnew[4], alpha[4];
        #pragma unroll
        for (int r = 0; r < 4; ++r) {
            s[0][r] *= 0.125f;                 // 1/sqrt(64)
            s[1][r] *= 0.125f;
            float t = fmaxf(s[0][r], s[1][r]);
            #pragma unroll
            for (int off = 1; off < 16; off <<= 1)
                t = fmaxf(t, __shfl_xor(t, off, 16));   // rows live in 16-lane groups
            mnew[r]  = fmaxf(mi[r], t);
            alpha[r] = __expf(mi[r] - mnew[r]);
            s[0][r]  = __expf(s[0][r] - mnew[r]);
            s[1][r]  = __expf(s[1][r] - mnew[r]);
            float rs = s[0][r] + s[1][r];
            #pragma unroll
            for (int off = 1; off < 16; off <<= 1)
                rs += __shfl_xor(rs, off, 16);
            li[r] = li[r] * alpha[r] + rs;
            mi[r] = mnew[r];
        }
        #pragma unroll
        for (int dt = 0; dt < 4; ++dt)
            #pragma unroll
            for (int r = 0; r < 4; ++r)
                acc[dt][r] *= alpha[r];

        // P: C-layout regs -> LDS -> A-layout frag (verified m120 pattern)
        #pragma unroll
        for (int jt = 0; jt < 2; ++jt)
            #pragma unroll
            for (int r = 0; r < 4; ++r)
                Plds[w][lq * 4 + r][jt * 16 + lr] = __float2bfloat16(s[jt][r]);
        __syncthreads();
        short8 ap = *(const short8*)(&Plds[w][lr][lq * 8]);
        #pragma unroll
        for (int dt = 0; dt < 4; ++dt) {
            short8 bv = *(const short8*)(Vh + (dt * 16 + lr) * SEQ + j0 + lq * 8);
            acc[dt] = __builtin_amdgcn_mfma_f32_16x16x32_bf16(ap, bv, acc[dt], 0, 0, 0);
        }
        __syncthreads();   // reads done before next iter's P write
    }

    #pragma unroll
    for (int r = 0; r < 4; ++r) li[r] = 1.f / li[r];
    #pragma unroll
    for (int dt = 0; dt < 4; ++dt)
        #pragma unroll
        for (int r = 0; r < 4; ++r) {
            int qi = m0 + lq * 4 + r;
            O[((size_t)b * SEQ + qi) * DM + h * DH + dt * 16 + lr] =
                __float2bfloat16(acc[dt][r] * li[r]);
        }
}

// ---------------------------------------------------------------------------
// Output projection: O(32768x768 bf16) @ Wproj + b -> out (fp32 row-major)
// ---------------------------------------------------------------------------
__global__ __launch_bounds__(256) void gemm_proj(
    const bf16* __restrict__ A, const bf16* __restrict__ WT,
    const float* __restrict__ bias, float* __restrict__ out)
{
    int w = threadIdx.x >> 6, lane = threadIdx.x & 63;
    int lr = lane & 15, lq = lane >> 4;
    int m0 = blockIdx.x * 64 + w * 16;
    int n0 = blockIdx.y * 64;

    const bf16* arow = A + (size_t)(m0 + lr) * DM;
    floatx4 acc[4] = {};
    for (int k0 = 0; k0 < DM; k0 += 32) {
        short8 a = *(const short8*)(arow + k0 + lq * 8);
        #pragma unroll
        for (int nt = 0; nt < 4; ++nt) {
            short8 bfr = *(const short8*)(WT + (size_t)(n0 + nt * 16 + lr) * DM + k0 + lq * 8);
            acc[nt] = __builtin_amdgcn_mfma_f32_16x16x32_bf16(a, bfr, acc[nt], 0, 0, 0);
        }
    }
    #pragma unroll
    for (int nt = 0; nt < 4; ++nt) {
        float bv = bias[n0 + nt * 16 + lr];
        #pragma unroll
        for (int r = 0; r < 4; ++r) {
            int rg = m0 + lq * 4 + r;
            out[(size_t)rg * DM + n0 + nt * 16 + lr] = acc[nt][r] + bv;
        }
    }
}

// ---------------------------------------------------------------------------
extern "C" void kernel_launch(void* const* d_in, const int* in_sizes, int n_in,
                              void* d_out, int out_size, void* d_ws, size_t ws_size,
                              hipStream_t stream)
{
    const float* x      = (const float*)d_in[0];
    const float* w_qkv  = (const float*)d_in[1];
    const float* b_qkv  = (const float*)d_in[2];
    const float* w_proj = (const float*)d_in[3];
    const float* b_proj = (const float*)d_in[4];
    float* out = (float*)d_out;

    // workspace layout (bf16 elems): wqkvT | wprojT | Xb | Q | K | Vt | O  (~236 MiB)
    bf16* ws = (bf16*)d_ws;
    size_t off = 0;
    bf16* wqkvT  = ws + off; off += (size_t)CQKV * DM;
    bf16* wprojT = ws + off; off += (size_t)DM * DM;
    bf16* Xb  = ws + off; off += (size_t)MROWS * DM;
    bf16* Qb  = ws + off; off += (size_t)BQ * NH * SEQ * DH;
    bf16* Kb  = ws + off; off += (size_t)BQ * NH * SEQ * DH;
    bf16* Vtb = ws + off; off += (size_t)BQ * NH * DH * SEQ;
    bf16* Ob  = ws + off; off += (size_t)MROWS * DM;

    cast_f32_bf16<<<(MROWS * DM / 4 + 255) / 256, 256, 0, stream>>>(x, Xb, MROWS * DM / 4);
    transpose_cast<<<(DM * CQKV + 255) / 256, 256, 0, stream>>>(w_qkv, wqkvT, DM, CQKV);
    transpose_cast<<<(DM * DM + 255) / 256, 256, 0, stream>>>(w_proj, wprojT, DM, DM);
    gemm_qkv<<<dim3(MROWS / 64, CQKV / 64), 256, 0, stream>>>(Xb, wqkvT, b_qkv, Qb, Kb, Vtb);
    flash_attn<<<dim3(SEQ / 64, NH, BQ), 256, 0, stream>>>(Qb, Kb, Vtb, Ob);
    gemm_proj<<<dim3(MROWS / 64, DM / 64), 256, 0, stream>>>(Ob, wprojT, b_proj, out);
}

// Round 3
// 1098.691 us; speedup vs baseline: 1.9956x; 1.9956x over previous
//
#include <hip/hip_runtime.h>
#include <hip/hip_bf16.h>

#define BQ   32
#define SEQ  1024
#define DM   768
#define NH   12
#define DH   64
#define CQKV 2304
#define MROWS (BQ * SEQ)   // 32768

typedef __attribute__((ext_vector_type(8))) short  short8;   // 8 bf16 = 4 VGPRs
typedef __attribute__((ext_vector_type(4))) short  short4v;  // 8 B
typedef __attribute__((ext_vector_type(4))) float  floatx4;

using bf16 = __hip_bfloat16;

// global -> LDS async copy, 16 B per lane. LDS dest is wave-uniform base +
// lane*16 (m104) — our LDS layout is exact lane order, no padding.
#define G2L(g, l) __builtin_amdgcn_global_load_lds(                              \
        (const __attribute__((address_space(1))) void*)(g),                      \
        (__attribute__((address_space(3))) void*)(l), 16, 0, 0)

#define WAVE_SYNC() __builtin_amdgcn_wave_barrier()

// ---------------------------------------------------------------------------
// Cast fp32 -> bf16, vectorized 4/thread.
// ---------------------------------------------------------------------------
__global__ void cast_f32_bf16(const float* __restrict__ in, bf16* __restrict__ out,
                              int n4)
{
    int idx = blockIdx.x * blockDim.x + threadIdx.x;
    if (idx < n4) {
        float4 v = ((const float4*)in)[idx];
        bf16 o[4] = { __float2bfloat16(v.x), __float2bfloat16(v.y),
                      __float2bfloat16(v.z), __float2bfloat16(v.w) };
        ((ushort4*)out)[idx] = *(const ushort4*)o;
    }
}

// ---------------------------------------------------------------------------
// Transpose+cast: fp32 (R x C) -> bf16 (C x R).
// ---------------------------------------------------------------------------
__global__ void transpose_cast(const float* __restrict__ in, bf16* __restrict__ out,
                               int R, int C)
{
    int idx = blockIdx.x * blockDim.x + threadIdx.x;
    if (idx < R * C) {
        int r = idx / C, c = idx % C;
        out[(size_t)c * R + r] = __float2bfloat16(in[idx]);
    }
}

// ---------------------------------------------------------------------------
// m97-style GEMM mainloop (shared by qkv / proj kernels via macro-ish inline):
// 128x128 tile, BK=32, 4 waves; wave w computes 64x64 at (w>>1, w&1).
// LDS As/Bs are [128][32] bf16, staged with global_load_lds width=16.
// ---------------------------------------------------------------------------
__device__ __forceinline__ void gemm_mainloop(
    const bf16* __restrict__ X, const bf16* __restrict__ WT,
    int m0, int n0, int t, int w, int lr, int lq,
    bf16* As, bf16* Bs, floatx4 acc[4][4])
{
    const int wm = (w >> 1) * 64, wn = (w & 1) * 64;
    // staging addresses: chunk c = p*256 + t; row = c>>2; 16B col chunk = c&3
    const bf16* gA = X  + (size_t)(m0 + (t >> 2)) * DM + (t & 3) * 8;
    const bf16* gB = WT + (size_t)(n0 + (t >> 2)) * DM + (t & 3) * 8;
    bf16* lA = As + w * 512;   // wave-uniform; lanes land at +lane*16B
    bf16* lB = Bs + w * 512;

    for (int k0 = 0; k0 < DM; k0 += 32) {
        G2L(gA + k0,           lA);
        G2L(gA + 64 * DM + k0, lA + 2048);
        G2L(gB + k0,           lB);
        G2L(gB + 64 * DM + k0, lB + 2048);
        __syncthreads();                       // drains vmcnt, staging visible
        short8 af[4], bfr[4];
        #pragma unroll
        for (int at = 0; at < 4; ++at)
            af[at] = *(const short8*)(As + (wm + at * 16 + lr) * 32 + lq * 8);
        #pragma unroll
        for (int bt = 0; bt < 4; ++bt)
            bfr[bt] = *(const short8*)(Bs + (wn + bt * 16 + lr) * 32 + lq * 8);
        #pragma unroll
        for (int at = 0; at < 4; ++at)
            #pragma unroll
            for (int bt = 0; bt < 4; ++bt)
                acc[at][bt] = __builtin_amdgcn_mfma_f32_16x16x32_bf16(
                                  af[at], bfr[bt], acc[at][bt], 0, 0, 0);
        __syncthreads();                       // reads done before next stage
    }
}

// ---------------------------------------------------------------------------
// QKV projection -> Q[b,h,n,d], K[b,h,n,d], Vt[b,h,d,n]
// Grid: (MROWS/128, CQKV/128). Each wave's 64-col subtile is within one head
// and one of q/k/v (cols 64-aligned, DH=64, DM=768 all multiples of 64).
// ---------------------------------------------------------------------------
__global__ __launch_bounds__(256) void gemm_qkv(
    const bf16* __restrict__ X, const bf16* __restrict__ WT,
    const float* __restrict__ bias,
    bf16* __restrict__ Qo, bf16* __restrict__ Ko, bf16* __restrict__ Vt)
{
    __shared__ __align__(16) bf16 As[4096], Bs[4096];
    const int t = threadIdx.x, w = t >> 6, lane = t & 63;
    const int lr = lane & 15, lq = lane >> 4;
    const int m0 = blockIdx.x * 128, n0 = blockIdx.y * 128;

    floatx4 acc[4][4] = {};
    gemm_mainloop(X, WT, m0, n0, t, w, lr, lq, As, Bs, acc);

    const int wm = (w >> 1) * 64, wn = (w & 1) * 64;
    const int cb = n0 + wn;                    // 64-aligned col base
    const int which = cb / DM;
    const int hb    = (cb % DM) / DH;
    #pragma unroll
    for (int bt = 0; bt < 4; ++bt) {
        const int d = bt * 16 + lr;
        const float bv = bias[cb + bt * 16 + lr];
        #pragma unroll
        for (int at = 0; at < 4; ++at) {
            const int nb = m0 + wm + at * 16 + lq * 4;   // 4 consecutive rows
            const int bb = nb >> 10, n = nb & (SEQ - 1); // same batch (nb%4==0)
            const size_t head = (size_t)bb * NH + hb;
            if (which == 2) {
                bf16 pk[4];
                #pragma unroll
                for (int rr = 0; rr < 4; ++rr)
                    pk[rr] = __float2bfloat16(acc[at][bt][rr] + bv);
                *(short4v*)(Vt + (head * DH + d) * SEQ + n) = *(const short4v*)pk;
            } else {
                bf16* base = (which ? Ko : Qo) + (head * SEQ + n) * DH + d;
                #pragma unroll
                for (int rr = 0; rr < 4; ++rr)
                    base[(size_t)rr * DH] = __float2bfloat16(acc[at][bt][rr] + bv);
            }
        }
    }
}

// ---------------------------------------------------------------------------
// Output projection: O(32768x768 bf16) @ Wproj + b -> out (fp32 row-major)
// ---------------------------------------------------------------------------
__global__ __launch_bounds__(256) void gemm_proj(
    const bf16* __restrict__ A, const bf16* __restrict__ WT,
    const float* __restrict__ bias, float* __restrict__ out)
{
    __shared__ __align__(16) bf16 As[4096], Bs[4096];
    const int t = threadIdx.x, w = t >> 6, lane = t & 63;
    const int lr = lane & 15, lq = lane >> 4;
    const int m0 = blockIdx.x * 128, n0 = blockIdx.y * 128;

    floatx4 acc[4][4] = {};
    gemm_mainloop(A, WT, m0, n0, t, w, lr, lq, As, Bs, acc);

    const int wm = (w >> 1) * 64, wn = (w & 1) * 64;
    #pragma unroll
    for (int bt = 0; bt < 4; ++bt) {
        const float bv = bias[n0 + wn + bt * 16 + lr];
        #pragma unroll
        for (int at = 0; at < 4; ++at) {
            const int rg = m0 + wm + at * 16 + lq * 4;
            #pragma unroll
            for (int rr = 0; rr < 4; ++rr)
                out[(size_t)(rg + rr) * DM + n0 + wn + bt * 16 + lr] =
                    acc[at][bt][rr] + bv;
        }
    }
}

// ---------------------------------------------------------------------------
// Flash attention. Grid: (SEQ/64, NH, BQ). Block 256 = 4 waves; wave owns 16
// q-rows. KV tiles of 64. Online softmax with width-16 shuffles. P goes
// C-layout -> A-layout through per-wave LDS (wave-internal, no block barrier
// needed: LDS ops of a wave are in-order; WAVE_SYNC pins compile-time order).
// ---------------------------------------------------------------------------
__global__ __launch_bounds__(256) void flash_attn(
    const bf16* __restrict__ Q, const bf16* __restrict__ K,
    const bf16* __restrict__ Vt, bf16* __restrict__ O)
{
    __shared__ __align__(16) bf16 Plds[4][16][72];   // per-wave 16x64 P (+8 pad)
    const int w = threadIdx.x >> 6, lane = threadIdx.x & 63;
    const int lr = lane & 15, lq = lane >> 4;
    const int b = blockIdx.z, h = blockIdx.y;
    const int m0 = blockIdx.x * 64 + w * 16;

    const bf16* Qh = Q  + (size_t)(b * NH + h) * SEQ * DH;
    const bf16* Kh = K  + (size_t)(b * NH + h) * SEQ * DH;
    const bf16* Vh = Vt + (size_t)(b * NH + h) * DH * SEQ;

    const short8 aq0 = *(const short8*)(Qh + (m0 + lr) * DH + lq * 8);
    const short8 aq1 = *(const short8*)(Qh + (m0 + lr) * DH + 32 + lq * 8);

    floatx4 acc[4] = {};
    float mi[4], li[4];
    #pragma unroll
    for (int r = 0; r < 4; ++r) { mi[r] = -1e30f; li[r] = 0.f; }

    for (int j0 = 0; j0 < SEQ; j0 += 64) {
        floatx4 s[4];
        #pragma unroll
        for (int jt = 0; jt < 4; ++jt) {
            const bf16* krow = Kh + (j0 + jt * 16 + lr) * DH;
            short8 bk0 = *(const short8*)(krow + lq * 8);
            short8 bk1 = *(const short8*)(krow + 32 + lq * 8);
            floatx4 c = {};
            c = __builtin_amdgcn_mfma_f32_16x16x32_bf16(aq0, bk0, c, 0, 0, 0);
            c = __builtin_amdgcn_mfma_f32_16x16x32_bf16(aq1, bk1, c, 0, 0, 0);
            s[jt] = c;
        }
        float alpha[4];
        #pragma unroll
        for (int r = 0; r < 4; ++r) {
            #pragma unroll
            for (int jt = 0; jt < 4; ++jt) s[jt][r] *= 0.125f;   // 1/sqrt(64)
            float tmax = fmaxf(fmaxf(s[0][r], s[1][r]), fmaxf(s[2][r], s[3][r]));
            #pragma unroll
            for (int off = 1; off < 16; off <<= 1)
                tmax = fmaxf(tmax, __shfl_xor(tmax, off, 16));
            const float mnew = fmaxf(mi[r], tmax);
            alpha[r] = __expf(mi[r] - mnew);
            float rs = 0.f;
            #pragma unroll
            for (int jt = 0; jt < 4; ++jt) {
                s[jt][r] = __expf(s[jt][r] - mnew);
                rs += s[jt][r];
            }
            #pragma unroll
            for (int off = 1; off < 16; off <<= 1)
                rs += __shfl_xor(rs, off, 16);
            li[r] = li[r] * alpha[r] + rs;
            mi[r] = mnew;
        }
        #pragma unroll
        for (int dt = 0; dt < 4; ++dt)
            #pragma unroll
            for (int r = 0; r < 4; ++r)
                acc[dt][r] *= alpha[r];

        // P: C-layout regs -> per-wave LDS -> A-layout frags (m120 pattern)
        #pragma unroll
        for (int jt = 0; jt < 4; ++jt)
            #pragma unroll
            for (int r = 0; r < 4; ++r)
                Plds[w][lq * 4 + r][jt * 16 + lr] = __float2bfloat16(s[jt][r]);
        WAVE_SYNC();
        const short8 ap0 = *(const short8*)(&Plds[w][lr][lq * 8]);
        const short8 ap1 = *(const short8*)(&Plds[w][lr][32 + lq * 8]);
        WAVE_SYNC();
        #pragma unroll
        for (int dt = 0; dt < 4; ++dt) {
            const bf16* vrow = Vh + (size_t)(dt * 16 + lr) * SEQ + j0;
            short8 bv0 = *(const short8*)(vrow + lq * 8);
            short8 bv1 = *(const short8*)(vrow + 32 + lq * 8);
            acc[dt] = __builtin_amdgcn_mfma_f32_16x16x32_bf16(ap0, bv0, acc[dt], 0, 0, 0);
            acc[dt] = __builtin_amdgcn_mfma_f32_16x16x32_bf16(ap1, bv1, acc[dt], 0, 0, 0);
        }
    }

    #pragma unroll
    for (int r = 0; r < 4; ++r) li[r] = 1.f / li[r];
    #pragma unroll
    for (int dt = 0; dt < 4; ++dt)
        #pragma unroll
        for (int r = 0; r < 4; ++r) {
            const int qi = m0 + lq * 4 + r;
            O[((size_t)b * SEQ + qi) * DM + h * DH + dt * 16 + lr] =
                __float2bfloat16(acc[dt][r] * li[r]);
        }
}

// ---------------------------------------------------------------------------
extern "C" void kernel_launch(void* const* d_in, const int* in_sizes, int n_in,
                              void* d_out, int out_size, void* d_ws, size_t ws_size,
                              hipStream_t stream)
{
    const float* x      = (const float*)d_in[0];
    const float* w_qkv  = (const float*)d_in[1];
    const float* b_qkv  = (const float*)d_in[2];
    const float* w_proj = (const float*)d_in[3];
    const float* b_proj = (const float*)d_in[4];
    float* out = (float*)d_out;

    // workspace layout (bf16 elems): wqkvT | wprojT | Xb | Q | K | Vt | O
    bf16* ws = (bf16*)d_ws;
    size_t off = 0;
    bf16* wqkvT  = ws + off; off += (size_t)CQKV * DM;
    bf16* wprojT = ws + off; off += (size_t)DM * DM;
    bf16* Xb  = ws + off; off += (size_t)MROWS * DM;
    bf16* Qb  = ws + off; off += (size_t)BQ * NH * SEQ * DH;
    bf16* Kb  = ws + off; off += (size_t)BQ * NH * SEQ * DH;
    bf16* Vtb = ws + off; off += (size_t)BQ * NH * DH * SEQ;
    bf16* Ob  = ws + off; off += (size_t)MROWS * DM;

    cast_f32_bf16<<<(MROWS * DM / 4 + 255) / 256, 256, 0, stream>>>(x, Xb, MROWS * DM / 4);
    transpose_cast<<<(DM * CQKV + 255) / 256, 256, 0, stream>>>(w_qkv, wqkvT, DM, CQKV);
    transpose_cast<<<(DM * DM + 255) / 256, 256, 0, stream>>>(w_proj, wprojT, DM, DM);
    gemm_qkv<<<dim3(MROWS / 128, CQKV / 128), 256, 0, stream>>>(Xb, wqkvT, b_qkv, Qb, Kb, Vtb);
    flash_attn<<<dim3(SEQ / 64, NH, BQ), 256, 0, stream>>>(Qb, Kb, Vtb, Ob);
    gemm_proj<<<dim3(MROWS / 128, DM / 128), 256, 0, stream>>>(Ob, wprojT, b_proj, out);
}